// Round 1
// baseline (704.016 us; speedup 1.0000x reference)
//
#include <hip/hip_runtime.h>

#define Bb 32
#define Ll 1024
#define LMD 1024
#define Dd 128
#define Rr 3
#define NLAYER 2
#define Cc 8
#define Nn (Bb*Ll)          // 32768
#define Ee 524288
#define NSEG (Nn*Rr)        // 98304
#define LN_EPS 1e-5f

// ---------------- transpose lm_W [128,1024] -> Wt [1024,128] ----------------
__global__ __launch_bounds__(256) void transpose_lmW_kernel(
    const float* __restrict__ lmW, float* __restrict__ Wt)
{
    int idx = blockIdx.x * 256 + threadIdx.x;   // 0..131071
    int h = idx >> 10, d = idx & 1023;
    Wt[d * 128 + h] = lmW[idx];                 // coalesced read
}

// ---------------- pack Wc [512,128] = [W_rel(layer) ; W_root(layer)] --------
__global__ __launch_bounds__(256) void pack_Wc_kernel(
    const float* __restrict__ Wrel, const float* __restrict__ Wroot,
    float* __restrict__ Wc)
{
    int idx = blockIdx.x * 256 + threadIdx.x;   // 0..65535
    int k = idx >> 7;
    Wc[idx] = (k < 384) ? Wrel[idx] : Wroot[idx - 384 * 128];
}

// ---------------- GEMM: out[M,128] = relu(split-A[M,K] * B[K,128] + bias) ---
// A = [A1 (K1 cols) | A2 (K-K1 cols)], B row-major [K,128].
__global__ __launch_bounds__(256) void gemm_bias_relu_kernel(
    const float* __restrict__ A1, int lda1, int K1,
    const float* __restrict__ A2, int lda2,
    const float* __restrict__ Bm, const float* __restrict__ bias,
    float* __restrict__ out, int K)
{
    __shared__ float As[64][36];    // 64 rows x 32 k (+pad)
    __shared__ float Bs[32][132];   // 32 k x 128 cols (+pad)
    const int t  = threadIdx.x;
    const int tx = t & 15;          // col group: cols tx*8 .. tx*8+7
    const int ty = t >> 4;          // row group: rows ty*4 .. ty*4+3
    const int row0 = blockIdx.x * 64;

    float acc[4][8];
    #pragma unroll
    for (int i = 0; i < 4; ++i)
        #pragma unroll
        for (int j = 0; j < 8; ++j) acc[i][j] = 0.f;

    for (int k0 = 0; k0 < K; k0 += 32) {
        const float* src; int lda, kc;
        if (k0 < K1) { src = A1; lda = lda1; kc = k0; }
        else         { src = A2; lda = lda2; kc = k0 - K1; }
        #pragma unroll
        for (int i = 0; i < 2; ++i) {           // A tile: 512 float4
            int idx = t + i * 256;
            int r = idx >> 3, c4 = idx & 7;
            float4 v = *(const float4*)(src + (size_t)(row0 + r) * lda + kc + c4 * 4);
            *(float4*)(&As[r][c4 * 4]) = v;
        }
        #pragma unroll
        for (int i = 0; i < 4; ++i) {           // B tile: 1024 float4
            int idx = t + i * 256;
            int r = idx >> 5, c4 = idx & 31;
            float4 v = *(const float4*)(Bm + (size_t)(k0 + r) * 128 + c4 * 4);
            *(float4*)(&Bs[r][c4 * 4]) = v;
        }
        __syncthreads();
        #pragma unroll
        for (int kk = 0; kk < 32; ++kk) {
            float a[4];
            #pragma unroll
            for (int i = 0; i < 4; ++i) a[i] = As[ty * 4 + i][kk];
            float4 b0 = *(const float4*)(&Bs[kk][tx * 8]);
            float4 b1 = *(const float4*)(&Bs[kk][tx * 8 + 4]);
            float b[8] = {b0.x, b0.y, b0.z, b0.w, b1.x, b1.y, b1.z, b1.w};
            #pragma unroll
            for (int i = 0; i < 4; ++i)
                #pragma unroll
                for (int j = 0; j < 8; ++j)
                    acc[i][j] = fmaf(a[i], b[j], acc[i][j]);
        }
        __syncthreads();
    }
    #pragma unroll
    for (int i = 0; i < 4; ++i) {
        int row = row0 + ty * 4 + i;
        float4 o0, o1;
        o0.x = fmaxf(acc[i][0] + bias[tx * 8 + 0], 0.f);
        o0.y = fmaxf(acc[i][1] + bias[tx * 8 + 1], 0.f);
        o0.z = fmaxf(acc[i][2] + bias[tx * 8 + 2], 0.f);
        o0.w = fmaxf(acc[i][3] + bias[tx * 8 + 3], 0.f);
        o1.x = fmaxf(acc[i][4] + bias[tx * 8 + 4], 0.f);
        o1.y = fmaxf(acc[i][5] + bias[tx * 8 + 5], 0.f);
        o1.z = fmaxf(acc[i][6] + bias[tx * 8 + 6], 0.f);
        o1.w = fmaxf(acc[i][7] + bias[tx * 8 + 7], 0.f);
        *(float4*)(out + (size_t)row * 128 + tx * 8)     = o0;
        *(float4*)(out + (size_t)row * 128 + tx * 8 + 4) = o1;
    }
}

// ---------------- LayerNorm in place over D=128 (one wave per row) ----------
__global__ __launch_bounds__(256) void ln_kernel(
    float* __restrict__ lm, const float* __restrict__ g, const float* __restrict__ b)
{
    int row  = blockIdx.x * 4 + (threadIdx.x >> 6);
    int lane = threadIdx.x & 63;
    float* p = lm + (size_t)row * Dd + lane * 2;
    float2 v = *(float2*)p;
    float s = v.x + v.y;
    #pragma unroll
    for (int off = 32; off > 0; off >>= 1) s += __shfl_xor(s, off, 64);
    float mu = s * (1.f / 128.f);
    float dx = v.x - mu, dy = v.y - mu;
    float q = dx * dx + dy * dy;
    #pragma unroll
    for (int off = 32; off > 0; off >>= 1) q += __shfl_xor(q, off, 64);
    float rs = rsqrtf(q * (1.f / 128.f) + LN_EPS);
    float2 o;
    o.x = dx * rs * g[lane * 2]     + b[lane * 2];
    o.y = dy * rs * g[lane * 2 + 1] + b[lane * 2 + 1];
    *(float2*)p = o;
}

// ---------------- CSR build ----------------
__global__ __launch_bounds__(256) void hist_kernel(
    const int* __restrict__ dst, const int* __restrict__ et, int* __restrict__ counts)
{
    int e = blockIdx.x * 256 + threadIdx.x;
    atomicAdd(&counts[dst[e] * 3 + et[e]], 1);
}

__global__ __launch_bounds__(1024) void scan_kernel(
    const int* __restrict__ counts, int* __restrict__ row_ptr)
{
    __shared__ int sums[1024];
    const int t = threadIdx.x;
    const int CH = NSEG / 1024;   // 96
    int base = t * CH;
    int s = 0;
    for (int i = 0; i < CH; ++i) s += counts[base + i];
    sums[t] = s;
    __syncthreads();
    for (int off = 1; off < 1024; off <<= 1) {
        int v = sums[t];
        int add = (t >= off) ? sums[t - off] : 0;
        __syncthreads();
        sums[t] = v + add;
        __syncthreads();
    }
    int run = (t == 0) ? 0 : sums[t - 1];
    for (int i = 0; i < CH; ++i) { row_ptr[base + i] = run; run += counts[base + i]; }
    if (t == 1023) row_ptr[NSEG] = run;
}

__global__ __launch_bounds__(256) void scatter_kernel(
    const int* __restrict__ src, const int* __restrict__ dst, const int* __restrict__ et,
    const int* __restrict__ row_ptr, int* __restrict__ fill, int* __restrict__ edge_src)
{
    int e = blockIdx.x * 256 + threadIdx.x;
    int s = dst[e] * 3 + et[e];
    int pos = row_ptr[s] + atomicAdd(&fill[s], 1);
    edge_src[pos] = src[e];
}

// ---------------- per-(node,relation) mean aggregation (one wave/segment) ---
__global__ __launch_bounds__(256) void aggregate_kernel(
    const float* __restrict__ x, const int* __restrict__ row_ptr,
    const int* __restrict__ edge_src, float* __restrict__ agg)
{
    int seg  = blockIdx.x * 4 + (threadIdx.x >> 6);
    int lane = threadIdx.x & 63;
    int b = row_ptr[seg], e = row_ptr[seg + 1];
    int n = seg / 3, r = seg - n * 3;
    float ax = 0.f, ay = 0.f;
    for (int i = b; i < e; ++i) {
        int sn = edge_src[i];
        float2 v = *(const float2*)(x + (size_t)sn * 128 + lane * 2);
        ax += v.x; ay += v.y;
    }
    int cnt = e - b;
    float inv = 1.f / (float)(cnt > 0 ? cnt : 1);
    float2 o; o.x = ax * inv; o.y = ay * inv;
    *(float2*)(agg + (size_t)n * 384 + r * 128 + lane * 2) = o;
}

// ---------------- classifier + masked CE loss ----------------
__global__ __launch_bounds__(256) void cls_loss_kernel(
    const float* __restrict__ lm, const float* __restrict__ g,
    const float* __restrict__ clsW, const float* __restrict__ clsb,
    const int* __restrict__ mask, const int* __restrict__ labels,
    float* __restrict__ logits, float* __restrict__ accb)
{
    __shared__ float W[2048];
    for (int i = threadIdx.x; i < 2048; i += 256) W[i] = clsW[i];
    __syncthreads();
    int n = blockIdx.x * 256 + threadIdx.x;
    float l[8];
    #pragma unroll
    for (int c = 0; c < 8; ++c) l[c] = clsb[c];
    const float* lmr = lm + (size_t)n * 128;
    const float* gr  = g  + (size_t)n * 128;
    #pragma unroll 4
    for (int h = 0; h < 128; h += 4) {
        float4 a = *(const float4*)(lmr + h);
        #pragma unroll
        for (int c = 0; c < 8; ++c) {
            const float* w = &W[c * 256 + h];
            l[c] = fmaf(a.x, w[0], l[c]); l[c] = fmaf(a.y, w[1], l[c]);
            l[c] = fmaf(a.z, w[2], l[c]); l[c] = fmaf(a.w, w[3], l[c]);
        }
    }
    #pragma unroll 4
    for (int h = 0; h < 128; h += 4) {
        float4 a = *(const float4*)(gr + h);
        #pragma unroll
        for (int c = 0; c < 8; ++c) {
            const float* w = &W[c * 256 + 128 + h];
            l[c] = fmaf(a.x, w[0], l[c]); l[c] = fmaf(a.y, w[1], l[c]);
            l[c] = fmaf(a.z, w[2], l[c]); l[c] = fmaf(a.w, w[3], l[c]);
        }
    }
    #pragma unroll
    for (int c = 0; c < 8; ++c) logits[(size_t)n * 8 + c] = l[c];

    float m = l[0];
    #pragma unroll
    for (int c = 1; c < 8; ++c) m = fmaxf(m, l[c]);
    float ss = 0.f;
    #pragma unroll
    for (int c = 0; c < 8; ++c) ss += expf(l[c] - m);
    float lse = m + logf(ss);
    int y = labels[n];
    float ly = l[0];
    #pragma unroll
    for (int c = 1; c < 8; ++c) ly = (y == c) ? l[c] : ly;
    float nll = lse - ly;
    bool valid = (mask[n] == 1);
    float lv = valid ? nll : 0.f;
    float cv = valid ? 1.f : 0.f;
    #pragma unroll
    for (int off = 32; off > 0; off >>= 1) {
        lv += __shfl_down(lv, off, 64);
        cv += __shfl_down(cv, off, 64);
    }
    if ((threadIdx.x & 63) == 0) { atomicAdd(&accb[0], lv); atomicAdd(&accb[1], cv); }
}

__global__ void finalize_kernel(const float* __restrict__ accb, float* __restrict__ out)
{
    out[0] = accb[0] / fmaxf(accb[1], 1.f);
}

// ---------------- launcher ----------------
extern "C" void kernel_launch(void* const* d_in, const int* in_sizes, int n_in,
                              void* d_out, int out_size, void* d_ws, size_t ws_size,
                              hipStream_t stream)
{
    const float* output = (const float*)d_in[0];
    const int* edge_index = (const int*)d_in[1];
    const int* edge_type  = (const int*)d_in[2];
    const int* attn       = (const int*)d_in[3];
    const int* labels     = (const int*)d_in[4];
    const float* lmW   = (const float*)d_in[5];
    const float* lmb   = (const float*)d_in[6];
    const float* lng   = (const float*)d_in[7];
    const float* lnb   = (const float*)d_in[8];
    const float* Wrel  = (const float*)d_in[9];
    const float* Wroot = (const float*)d_in[10];
    const float* convb = (const float*)d_in[11];
    const float* clsW  = (const float*)d_in[12];
    const float* clsb  = (const float*)d_in[13];

    float* ws   = (float*)d_ws;
    float* lm   = ws;                           // N*128
    float* xbuf = lm   + (size_t)Nn * Dd;       // N*128
    float* agg  = xbuf + (size_t)Nn * Dd;       // N*384
    float* Wt   = agg  + (size_t)Nn * 384;      // 1024*128
    float* Wc   = Wt   + (size_t)LMD * Dd;      // 512*128
    float* accb = Wc   + (size_t)512 * Dd;      // 2 (+pad)
    int* row_ptr  = (int*)(accb + 8);           // NSEG+1 (+pad)
    int* counts   = row_ptr + (NSEG + 4);       // NSEG
    int* edge_src = counts + NSEG;              // E

    const int* e_src = edge_index;
    const int* e_dst = edge_index + Ee;

    hipMemsetAsync(counts, 0, NSEG * sizeof(int), stream);
    hipMemsetAsync(accb, 0, 2 * sizeof(float), stream);

    // LM head + ReLU + LN
    transpose_lmW_kernel<<<dim3(131072 / 256), dim3(256), 0, stream>>>(lmW, Wt);
    gemm_bias_relu_kernel<<<dim3(Nn / 64), dim3(256), 0, stream>>>(
        output, LMD, LMD, output, LMD, Wt, lmb, lm, LMD);
    ln_kernel<<<dim3(Nn / 4), dim3(256), 0, stream>>>(lm, lng, lnb);

    // CSR over (dst, relation)
    hist_kernel<<<dim3(Ee / 256), dim3(256), 0, stream>>>(e_dst, edge_type, counts);
    scan_kernel<<<dim3(1), dim3(1024), 0, stream>>>(counts, row_ptr);
    hipMemsetAsync(counts, 0, NSEG * sizeof(int), stream);
    scatter_kernel<<<dim3(Ee / 256), dim3(256), 0, stream>>>(
        e_src, e_dst, edge_type, row_ptr, counts, edge_src);

    // RGCN layers
    const float* xin = lm;
    for (int layer = 0; layer < NLAYER; ++layer) {
        aggregate_kernel<<<dim3(NSEG / 4), dim3(256), 0, stream>>>(xin, row_ptr, edge_src, agg);
        pack_Wc_kernel<<<dim3(65536 / 256), dim3(256), 0, stream>>>(
            Wrel + (size_t)layer * Rr * Dd * Dd, Wroot + (size_t)layer * Dd * Dd, Wc);
        gemm_bias_relu_kernel<<<dim3(Nn / 64), dim3(256), 0, stream>>>(
            agg, 384, 384, xin, 128, Wc, convb + layer * Dd, xbuf, 512);
        xin = xbuf;
    }

    // classifier + loss
    float* logits = (float*)d_out + 1;
    cls_loss_kernel<<<dim3(Nn / 256), dim3(256), 0, stream>>>(
        lm, xbuf, clsW, clsb, attn, labels, logits, accb);
    finalize_kernel<<<dim3(1), dim3(1), 0, stream>>>(accb, (float*)d_out);
}

// Round 2
// 531.947 us; speedup vs baseline: 1.3235x; 1.3235x over previous
//
#include <hip/hip_runtime.h>

#define Bb 32
#define Ll 1024
#define LMD 1024
#define Dd 128
#define Rr 3
#define NLAYER 2
#define Cc 8
#define Nn (Bb*Ll)          // 32768
#define Ee 524288
#define NSEG (Nn*Rr)        // 98304
#define LN_EPS 1e-5f

typedef __attribute__((ext_vector_type(8))) short bf16x8;
typedef __attribute__((ext_vector_type(4))) float f32x4;

__device__ inline short f2bf(float f) {
    unsigned u = __builtin_bit_cast(unsigned, f);
    u += 0x7fff + ((u >> 16) & 1);           // RNE
    return (short)(u >> 16);
}
__device__ inline float bf2f(unsigned short s) {
    unsigned u = ((unsigned)s) << 16;
    return __builtin_bit_cast(float, u);
}

// ---- pack LM weight: Wp[ks][n][kk] = bf16(lm_W[n][ks*32+kk]), ks<32,n<128,kk<32
__global__ __launch_bounds__(256) void pack_lmW_kernel(
    const float* __restrict__ lmW, short* __restrict__ Wp)
{
    int idx = blockIdx.x * 256 + threadIdx.x;   // 0..131071
    int kk = idx & 31, n = (idx >> 5) & 127, ks = idx >> 12;
    Wp[idx] = f2bf(lmW[n * 1024 + ks * 32 + kk]);
}

// ---- pack conv weight: B[k][n], k = r*128+d (k<384: Wrel) else Wroot[k-384][n]
// Wp[ks][n][kk] = bf16(B[ks*32+kk][n]), ks<16, n<128, kk<32
__global__ __launch_bounds__(256) void pack_convW_kernel(
    const float* __restrict__ Wrel, const float* __restrict__ Wroot,
    short* __restrict__ Wp)
{
    int idx = blockIdx.x * 256 + threadIdx.x;   // 0..65535
    int kk = idx & 31, n = (idx >> 5) & 127, ks = idx >> 12;
    int k = ks * 32 + kk;
    float v = (k < 384) ? Wrel[(size_t)k * 128 + n] : Wroot[(size_t)(k - 384) * 128 + n];
    Wp[idx] = f2bf(v);
}

// ---- LM head GEMM (MFMA bf16) + bias + ReLU + fused LayerNorm ----
// out rows M=32768, cols 128, K=1024. Grid 512 blocks x 256 thr; wave = 16 rows.
__global__ __launch_bounds__(256) void lm_gemm_ln_kernel(
    const float* __restrict__ A,        // [M,1024] fp32
    const short* __restrict__ Wp,       // [32][128][32] bf16 frag-packed
    const float* __restrict__ bias,     // [128]
    const float* __restrict__ lng, const float* __restrict__ lnb,
    float* __restrict__ lm_f32, short* __restrict__ lm_bf16)
{
    const int wv   = threadIdx.x >> 6;
    const int lane = threadIdx.x & 63;
    const int m16  = lane & 15;
    const int quad = lane >> 4;
    const int row_frag = blockIdx.x * 64 + wv * 16 + m16;
    const float* arow = A + (size_t)row_frag * 1024 + quad * 8;

    f32x4 acc[8];
    #pragma unroll
    for (int i = 0; i < 8; ++i) acc[i] = (f32x4){0.f, 0.f, 0.f, 0.f};

    #pragma unroll 2
    for (int ks = 0; ks < 32; ++ks) {
        const short* wpb = Wp + ks * 4096 + m16 * 32 + quad * 8;
        bf16x8 bfr[8];
        #pragma unroll
        for (int nt = 0; nt < 8; ++nt)
            bfr[nt] = *(const bf16x8*)(wpb + nt * 512);
        const float4* ap = (const float4*)(arow + ks * 32);
        float4 a0 = ap[0], a1 = ap[1];
        union { bf16x8 v; short s[8]; } af;
        af.s[0] = f2bf(a0.x); af.s[1] = f2bf(a0.y);
        af.s[2] = f2bf(a0.z); af.s[3] = f2bf(a0.w);
        af.s[4] = f2bf(a1.x); af.s[5] = f2bf(a1.y);
        af.s[6] = f2bf(a1.z); af.s[7] = f2bf(a1.w);
        #pragma unroll
        for (int nt = 0; nt < 8; ++nt)
            acc[nt] = __builtin_amdgcn_mfma_f32_16x16x32_bf16(af.v, bfr[nt], acc[nt], 0, 0, 0);
    }

    // epilogue: bias + relu, then LayerNorm per row (row = quad*4 + r)
    float v[8][4];
    #pragma unroll
    for (int nt = 0; nt < 8; ++nt) {
        float bs = bias[nt * 16 + m16];
        #pragma unroll
        for (int r = 0; r < 4; ++r) v[nt][r] = fmaxf(acc[nt][r] + bs, 0.f);
    }
    float gv[8], bv[8];
    #pragma unroll
    for (int nt = 0; nt < 8; ++nt) { gv[nt] = lng[nt * 16 + m16]; bv[nt] = lnb[nt * 16 + m16]; }

    const int row0 = blockIdx.x * 64 + wv * 16 + quad * 4;
    #pragma unroll
    for (int r = 0; r < 4; ++r) {
        float s = 0.f;
        #pragma unroll
        for (int nt = 0; nt < 8; ++nt) s += v[nt][r];
        s += __shfl_xor(s, 1, 64); s += __shfl_xor(s, 2, 64);
        s += __shfl_xor(s, 4, 64); s += __shfl_xor(s, 8, 64);
        float mu = s * (1.f / 128.f);
        float q = 0.f;
        #pragma unroll
        for (int nt = 0; nt < 8; ++nt) { float d = v[nt][r] - mu; q += d * d; }
        q += __shfl_xor(q, 1, 64); q += __shfl_xor(q, 2, 64);
        q += __shfl_xor(q, 4, 64); q += __shfl_xor(q, 8, 64);
        float rs = rsqrtf(q * (1.f / 128.f) + LN_EPS);
        size_t rowoff = (size_t)(row0 + r) * 128;
        #pragma unroll
        for (int nt = 0; nt < 8; ++nt) {
            float o = (v[nt][r] - mu) * rs * gv[nt] + bv[nt];
            lm_f32[rowoff + nt * 16 + m16] = o;
            lm_bf16[rowoff + nt * 16 + m16] = f2bf(o);
        }
    }
}

// ---- conv GEMM (MFMA bf16): out = relu([agg|x] * Wc + bias), K=512, bf16 in/out
__global__ __launch_bounds__(256) void conv_gemm_kernel(
    const short* __restrict__ A1,       // [N,384] bf16 (agg)
    const short* __restrict__ A2,       // [N,128] bf16 (x)
    const short* __restrict__ Wp,       // [16][128][32] bf16 frag-packed
    const float* __restrict__ bias,
    short* __restrict__ out_bf16)       // [N,128]
{
    const int wv   = threadIdx.x >> 6;
    const int lane = threadIdx.x & 63;
    const int m16  = lane & 15;
    const int quad = lane >> 4;
    const int row_frag = blockIdx.x * 64 + wv * 16 + m16;
    const short* a1row = A1 + (size_t)row_frag * 384 + quad * 8;
    const short* a2row = A2 + (size_t)row_frag * 128 + quad * 8;

    f32x4 acc[8];
    #pragma unroll
    for (int i = 0; i < 8; ++i) acc[i] = (f32x4){0.f, 0.f, 0.f, 0.f};

    #pragma unroll 2
    for (int ks = 0; ks < 16; ++ks) {
        const short* wpb = Wp + ks * 4096 + m16 * 32 + quad * 8;
        bf16x8 bfr[8];
        #pragma unroll
        for (int nt = 0; nt < 8; ++nt)
            bfr[nt] = *(const bf16x8*)(wpb + nt * 512);
        const short* ar = (ks < 12) ? (a1row + ks * 32) : (a2row + (ks - 12) * 32);
        bf16x8 af = *(const bf16x8*)ar;
        #pragma unroll
        for (int nt = 0; nt < 8; ++nt)
            acc[nt] = __builtin_amdgcn_mfma_f32_16x16x32_bf16(af, bfr[nt], acc[nt], 0, 0, 0);
    }

    const int row0 = blockIdx.x * 64 + wv * 16 + quad * 4;
    #pragma unroll
    for (int nt = 0; nt < 8; ++nt) {
        float bs = bias[nt * 16 + m16];
        #pragma unroll
        for (int r = 0; r < 4; ++r) {
            float o = fmaxf(acc[nt][r] + bs, 0.f);
            out_bf16[(size_t)(row0 + r) * 128 + nt * 16 + m16] = f2bf(o);
        }
    }
}

// ---- CSR build ----
__global__ __launch_bounds__(256) void hist_kernel(
    const int* __restrict__ dst, const int* __restrict__ et, int* __restrict__ counts)
{
    int e = blockIdx.x * 256 + threadIdx.x;
    atomicAdd(&counts[dst[e] * 3 + et[e]], 1);
}

__global__ __launch_bounds__(1024) void scan_kernel(
    const int* __restrict__ counts, int* __restrict__ row_ptr)
{
    __shared__ int sums[1024];
    const int t = threadIdx.x;
    const int CH = NSEG / 1024;   // 96
    int base = t * CH;
    int s = 0;
    for (int i = 0; i < CH; ++i) s += counts[base + i];
    sums[t] = s;
    __syncthreads();
    for (int off = 1; off < 1024; off <<= 1) {
        int v = sums[t];
        int add = (t >= off) ? sums[t - off] : 0;
        __syncthreads();
        sums[t] = v + add;
        __syncthreads();
    }
    int run = (t == 0) ? 0 : sums[t - 1];
    for (int i = 0; i < CH; ++i) { row_ptr[base + i] = run; run += counts[base + i]; }
    if (t == 1023) row_ptr[NSEG] = run;
}

__global__ __launch_bounds__(256) void scatter_kernel(
    const int* __restrict__ src, const int* __restrict__ dst, const int* __restrict__ et,
    const int* __restrict__ row_ptr, int* __restrict__ fill, int* __restrict__ edge_src)
{
    int e = blockIdx.x * 256 + threadIdx.x;
    int s = dst[e] * 3 + et[e];
    int pos = row_ptr[s] + atomicAdd(&fill[s], 1);
    edge_src[pos] = src[e];
}

// ---- per-(node,relation) mean aggregation over bf16 x (one wave/segment) ----
__global__ __launch_bounds__(256) void aggregate_kernel(
    const short* __restrict__ x, const int* __restrict__ row_ptr,
    const int* __restrict__ edge_src, short* __restrict__ agg)
{
    int seg  = blockIdx.x * 4 + (threadIdx.x >> 6);
    int lane = threadIdx.x & 63;
    int b = row_ptr[seg], e = row_ptr[seg + 1];
    int n = seg / 3, r = seg - n * 3;
    float ax = 0.f, ay = 0.f;
    for (int i = b; i < e; ++i) {
        int sn = edge_src[i];
        unsigned u = *(const unsigned*)(x + (size_t)sn * 128 + lane * 2);
        ax += bf2f((unsigned short)(u & 0xffff));
        ay += bf2f((unsigned short)(u >> 16));
    }
    int cnt = e - b;
    float inv = 1.f / (float)(cnt > 0 ? cnt : 1);
    unsigned short lo = (unsigned short)f2bf(ax * inv);
    unsigned short hi = (unsigned short)f2bf(ay * inv);
    *(unsigned*)(agg + (size_t)n * 384 + r * 128 + lane * 2) = (unsigned)lo | ((unsigned)hi << 16);
}

// ---- classifier + masked CE loss (lm fp32, g bf16) ----
__global__ __launch_bounds__(256) void cls_loss_kernel(
    const float* __restrict__ lm, const short* __restrict__ g,
    const float* __restrict__ clsW, const float* __restrict__ clsb,
    const int* __restrict__ mask, const int* __restrict__ labels,
    float* __restrict__ logits, float* __restrict__ accb)
{
    __shared__ float W[2048];
    for (int i = threadIdx.x; i < 2048; i += 256) W[i] = clsW[i];
    __syncthreads();
    int n = blockIdx.x * 256 + threadIdx.x;
    float l[8];
    #pragma unroll
    for (int c = 0; c < 8; ++c) l[c] = clsb[c];
    const float* lmr = lm + (size_t)n * 128;
    const short* gr  = g  + (size_t)n * 128;
    #pragma unroll 4
    for (int h = 0; h < 128; h += 4) {
        float4 a = *(const float4*)(lmr + h);
        #pragma unroll
        for (int c = 0; c < 8; ++c) {
            const float* w = &W[c * 256 + h];
            l[c] = fmaf(a.x, w[0], l[c]); l[c] = fmaf(a.y, w[1], l[c]);
            l[c] = fmaf(a.z, w[2], l[c]); l[c] = fmaf(a.w, w[3], l[c]);
        }
    }
    #pragma unroll 2
    for (int h = 0; h < 128; h += 8) {
        uint4 raw = *(const uint4*)(gr + h);
        float a[8];
        a[0] = bf2f((unsigned short)(raw.x & 0xffff)); a[1] = bf2f((unsigned short)(raw.x >> 16));
        a[2] = bf2f((unsigned short)(raw.y & 0xffff)); a[3] = bf2f((unsigned short)(raw.y >> 16));
        a[4] = bf2f((unsigned short)(raw.z & 0xffff)); a[5] = bf2f((unsigned short)(raw.z >> 16));
        a[6] = bf2f((unsigned short)(raw.w & 0xffff)); a[7] = bf2f((unsigned short)(raw.w >> 16));
        #pragma unroll
        for (int c = 0; c < 8; ++c) {
            const float* w = &W[c * 256 + 128 + h];
            #pragma unroll
            for (int j = 0; j < 8; ++j) l[c] = fmaf(a[j], w[j], l[c]);
        }
    }
    #pragma unroll
    for (int c = 0; c < 8; ++c) logits[(size_t)n * 8 + c] = l[c];

    float m = l[0];
    #pragma unroll
    for (int c = 1; c < 8; ++c) m = fmaxf(m, l[c]);
    float ss = 0.f;
    #pragma unroll
    for (int c = 0; c < 8; ++c) ss += expf(l[c] - m);
    float lse = m + logf(ss);
    int y = labels[n];
    float ly = l[0];
    #pragma unroll
    for (int c = 1; c < 8; ++c) ly = (y == c) ? l[c] : ly;
    float nll = lse - ly;
    bool valid = (mask[n] == 1);
    float lv = valid ? nll : 0.f;
    float cv = valid ? 1.f : 0.f;
    #pragma unroll
    for (int off = 32; off > 0; off >>= 1) {
        lv += __shfl_down(lv, off, 64);
        cv += __shfl_down(cv, off, 64);
    }
    if ((threadIdx.x & 63) == 0) { atomicAdd(&accb[0], lv); atomicAdd(&accb[1], cv); }
}

__global__ void finalize_kernel(const float* __restrict__ accb, float* __restrict__ out)
{
    out[0] = accb[0] / fmaxf(accb[1], 1.f);
}

// ---- launcher ----
extern "C" void kernel_launch(void* const* d_in, const int* in_sizes, int n_in,
                              void* d_out, int out_size, void* d_ws, size_t ws_size,
                              hipStream_t stream)
{
    const float* output = (const float*)d_in[0];
    const int* edge_index = (const int*)d_in[1];
    const int* edge_type  = (const int*)d_in[2];
    const int* attn       = (const int*)d_in[3];
    const int* labels     = (const int*)d_in[4];
    const float* lmW   = (const float*)d_in[5];
    const float* lmb   = (const float*)d_in[6];
    const float* lng   = (const float*)d_in[7];
    const float* lnb   = (const float*)d_in[8];
    const float* Wrel  = (const float*)d_in[9];
    const float* Wroot = (const float*)d_in[10];
    const float* convb = (const float*)d_in[11];
    const float* clsW  = (const float*)d_in[12];
    const float* clsb  = (const float*)d_in[13];

    char* ws = (char*)d_ws;
    float* lm_f32 = (float*)ws;                          ws += (size_t)Nn * Dd * 4;
    short* lm_bf  = (short*)ws;                          ws += (size_t)Nn * Dd * 2;
    short* x1_bf  = (short*)ws;                          ws += (size_t)Nn * Dd * 2;
    short* x2_bf  = (short*)ws;                          ws += (size_t)Nn * Dd * 2;
    short* agg_bf = (short*)ws;                          ws += (size_t)Nn * 384 * 2;
    short* Wp_lm  = (short*)ws;                          ws += (size_t)131072 * 2;
    short* Wp_c0  = (short*)ws;                          ws += (size_t)65536 * 2;
    short* Wp_c1  = (short*)ws;                          ws += (size_t)65536 * 2;
    float* accb   = (float*)ws;                          ws += 64;
    int* row_ptr  = (int*)ws;                            ws += (size_t)(NSEG + 4) * 4;
    int* counts   = (int*)ws;                            ws += (size_t)NSEG * 4;
    int* edge_src = (int*)ws;

    const int* e_src = edge_index;
    const int* e_dst = edge_index + Ee;

    hipMemsetAsync(counts, 0, NSEG * sizeof(int), stream);
    hipMemsetAsync(accb, 0, 2 * sizeof(float), stream);

    // weight packs
    pack_lmW_kernel<<<dim3(512), dim3(256), 0, stream>>>(lmW, Wp_lm);
    pack_convW_kernel<<<dim3(256), dim3(256), 0, stream>>>(Wrel, Wroot, Wp_c0);
    pack_convW_kernel<<<dim3(256), dim3(256), 0, stream>>>(
        Wrel + (size_t)Rr * Dd * Dd, Wroot + (size_t)Dd * Dd, Wp_c1);

    // LM head + ReLU + fused LN
    lm_gemm_ln_kernel<<<dim3(Nn / 64), dim3(256), 0, stream>>>(
        output, Wp_lm, lmb, lng, lnb, lm_f32, lm_bf);

    // CSR over (dst, relation)
    hist_kernel<<<dim3(Ee / 256), dim3(256), 0, stream>>>(e_dst, edge_type, counts);
    scan_kernel<<<dim3(1), dim3(1024), 0, stream>>>(counts, row_ptr);
    hipMemsetAsync(counts, 0, NSEG * sizeof(int), stream);
    scatter_kernel<<<dim3(Ee / 256), dim3(256), 0, stream>>>(
        e_src, e_dst, edge_type, row_ptr, counts, edge_src);

    // RGCN layers
    aggregate_kernel<<<dim3(NSEG / 4), dim3(256), 0, stream>>>(lm_bf, row_ptr, edge_src, agg_bf);
    conv_gemm_kernel<<<dim3(Nn / 64), dim3(256), 0, stream>>>(
        agg_bf, lm_bf, Wp_c0, convb, x1_bf);
    aggregate_kernel<<<dim3(NSEG / 4), dim3(256), 0, stream>>>(x1_bf, row_ptr, edge_src, agg_bf);
    conv_gemm_kernel<<<dim3(Nn / 64), dim3(256), 0, stream>>>(
        agg_bf, x1_bf, Wp_c1, convb + Dd, x2_bf);

    // classifier + loss
    float* logits = (float*)d_out + 1;
    cls_loss_kernel<<<dim3(Nn / 256), dim3(256), 0, stream>>>(
        lm_f32, x2_bf, clsW, clsb, attn, labels, logits, accb);
    finalize_kernel<<<dim3(1), dim3(1), 0, stream>>>(accb, (float*)d_out);
}

// Round 4
// 487.825 us; speedup vs baseline: 1.4432x; 1.0904x over previous
//
#include <hip/hip_runtime.h>

#define Bb 32
#define Ll 1024
#define LMD 1024
#define Dd 128
#define Rr 3
#define NLAYER 2
#define Cc 8
#define Nn (Bb*Ll)          // 32768
#define Ee 524288
#define NSEG (Nn*Rr)        // 98304
#define LN_EPS 1e-5f

typedef __attribute__((ext_vector_type(8))) short bf16x8;
typedef __attribute__((ext_vector_type(4))) float f32x4;

__device__ inline short f2bf(float f) {
    unsigned u = __builtin_bit_cast(unsigned, f);
    u += 0x7fff + ((u >> 16) & 1);           // RNE
    return (short)(u >> 16);
}
__device__ inline float bf2f(unsigned short s) {
    unsigned u = ((unsigned)s) << 16;
    return __builtin_bit_cast(float, u);
}

// ---- one pack kernel for all weights ----
// Wp_all = [lm (131072) | conv0 (65536) | conv1 (65536)] bf16
// lm:   Wp[ks][n][kk] = bf16(lm_W[n][ks*32+kk]), ks<32,n<128,kk<32
// conv: Wp[ks][n][kk] = bf16(B[ks*32+kk][n]), B=[Wrel(layer);Wroot(layer)], ks<16
__global__ __launch_bounds__(256) void pack_all_kernel(
    const float* __restrict__ lmW, const float* __restrict__ Wrel,
    const float* __restrict__ Wroot, short* __restrict__ Wp_all)
{
    int idx = blockIdx.x * 256 + threadIdx.x;   // 0..262143
    float v;
    if (idx < 131072) {
        int kk = idx & 31, n = (idx >> 5) & 127, ks = idx >> 12;
        v = lmW[n * 1024 + ks * 32 + kk];
    } else {
        int j = idx - 131072;
        int layer = j >> 16;
        int kk = j & 31, n = (j >> 5) & 127, ks = (j >> 12) & 15;
        int k = ks * 32 + kk;
        v = (k < 384) ? Wrel[(size_t)layer * 49152 + (size_t)k * 128 + n]
                      : Wroot[(size_t)layer * 16384 + (size_t)(k - 384) * 128 + n];
    }
    Wp_all[idx] = f2bf(v);
}

// ---- LM head GEMM (MFMA bf16) + bias + ReLU + fused LayerNorm ----
// ROUND-2 VERBATIM (passing). M=32768, cols 128, K=1024. 512 blocks x 256 thr.
__global__ __launch_bounds__(256) void lm_gemm_ln_kernel(
    const float* __restrict__ A,        // [M,1024] fp32
    const short* __restrict__ Wp,       // [32][128][32] bf16 frag-packed
    const float* __restrict__ bias,     // [128]
    const float* __restrict__ lng, const float* __restrict__ lnb,
    float* __restrict__ lm_f32, short* __restrict__ lm_bf16)
{
    const int wv   = threadIdx.x >> 6;
    const int lane = threadIdx.x & 63;
    const int m16  = lane & 15;
    const int quad = lane >> 4;
    const int row_frag = blockIdx.x * 64 + wv * 16 + m16;
    const float* arow = A + (size_t)row_frag * 1024 + quad * 8;

    f32x4 acc[8];
    #pragma unroll
    for (int i = 0; i < 8; ++i) acc[i] = (f32x4){0.f, 0.f, 0.f, 0.f};

    #pragma unroll 2
    for (int ks = 0; ks < 32; ++ks) {
        const short* wpb = Wp + ks * 4096 + m16 * 32 + quad * 8;
        bf16x8 bfr[8];
        #pragma unroll
        for (int nt = 0; nt < 8; ++nt)
            bfr[nt] = *(const bf16x8*)(wpb + nt * 512);
        const float4* ap = (const float4*)(arow + ks * 32);
        float4 a0 = ap[0], a1 = ap[1];
        union { bf16x8 v; short s[8]; } af;
        af.s[0] = f2bf(a0.x); af.s[1] = f2bf(a0.y);
        af.s[2] = f2bf(a0.z); af.s[3] = f2bf(a0.w);
        af.s[4] = f2bf(a1.x); af.s[5] = f2bf(a1.y);
        af.s[6] = f2bf(a1.z); af.s[7] = f2bf(a1.w);
        #pragma unroll
        for (int nt = 0; nt < 8; ++nt)
            acc[nt] = __builtin_amdgcn_mfma_f32_16x16x32_bf16(af.v, bfr[nt], acc[nt], 0, 0, 0);
    }

    // epilogue: bias + relu, then LayerNorm per row (row = quad*4 + r)
    float v[8][4];
    #pragma unroll
    for (int nt = 0; nt < 8; ++nt) {
        float bs = bias[nt * 16 + m16];
        #pragma unroll
        for (int r = 0; r < 4; ++r) v[nt][r] = fmaxf(acc[nt][r] + bs, 0.f);
    }
    float gv[8], bv[8];
    #pragma unroll
    for (int nt = 0; nt < 8; ++nt) { gv[nt] = lng[nt * 16 + m16]; bv[nt] = lnb[nt * 16 + m16]; }

    const int row0 = blockIdx.x * 64 + wv * 16 + quad * 4;
    #pragma unroll
    for (int r = 0; r < 4; ++r) {
        float s = 0.f;
        #pragma unroll
        for (int nt = 0; nt < 8; ++nt) s += v[nt][r];
        s += __shfl_xor(s, 1, 64); s += __shfl_xor(s, 2, 64);
        s += __shfl_xor(s, 4, 64); s += __shfl_xor(s, 8, 64);
        float mu = s * (1.f / 128.f);
        float q = 0.f;
        #pragma unroll
        for (int nt = 0; nt < 8; ++nt) { float d = v[nt][r] - mu; q += d * d; }
        q += __shfl_xor(q, 1, 64); q += __shfl_xor(q, 2, 64);
        q += __shfl_xor(q, 4, 64); q += __shfl_xor(q, 8, 64);
        float rs = rsqrtf(q * (1.f / 128.f) + LN_EPS);
        size_t rowoff = (size_t)(row0 + r) * 128;
        #pragma unroll
        for (int nt = 0; nt < 8; ++nt) {
            float o = (v[nt][r] - mu) * rs * gv[nt] + bv[nt];
            lm_f32[rowoff + nt * 16 + m16] = o;
            lm_bf16[rowoff + nt * 16 + m16] = f2bf(o);
        }
    }
}

// ---- conv GEMM (MFMA bf16): out = relu([agg|x] * Wc + bias), K=512 ----
__global__ __launch_bounds__(256) void conv_gemm_kernel(
    const short* __restrict__ A1,       // [N,384] bf16 (agg)
    const short* __restrict__ A2,       // [N,128] bf16 (x)
    const short* __restrict__ Wp,       // [16][128][32] bf16 frag-packed
    const float* __restrict__ bias,
    short* __restrict__ out_bf16)       // [N,128]
{
    const int wv   = threadIdx.x >> 6;
    const int lane = threadIdx.x & 63;
    const int m16  = lane & 15;
    const int quad = lane >> 4;
    const int row_frag = blockIdx.x * 64 + wv * 16 + m16;
    const short* a1row = A1 + (size_t)row_frag * 384 + quad * 8;
    const short* a2row = A2 + (size_t)row_frag * 128 + quad * 8;

    f32x4 acc[8];
    #pragma unroll
    for (int i = 0; i < 8; ++i) acc[i] = (f32x4){0.f, 0.f, 0.f, 0.f};

    #pragma unroll 2
    for (int ks = 0; ks < 16; ++ks) {
        const short* wpb = Wp + ks * 4096 + m16 * 32 + quad * 8;
        bf16x8 bfr[8];
        #pragma unroll
        for (int nt = 0; nt < 8; ++nt)
            bfr[nt] = *(const bf16x8*)(wpb + nt * 512);
        const short* ar = (ks < 12) ? (a1row + ks * 32) : (a2row + (ks - 12) * 32);
        bf16x8 af = *(const bf16x8*)ar;
        #pragma unroll
        for (int nt = 0; nt < 8; ++nt)
            acc[nt] = __builtin_amdgcn_mfma_f32_16x16x32_bf16(af, bfr[nt], acc[nt], 0, 0, 0);
    }

    const int row0 = blockIdx.x * 64 + wv * 16 + quad * 4;
    #pragma unroll
    for (int nt = 0; nt < 8; ++nt) {
        float bs = bias[nt * 16 + m16];
        #pragma unroll
        for (int r = 0; r < 4; ++r) {
            float o = fmaxf(acc[nt][r] + bs, 0.f);
            out_bf16[(size_t)(row0 + r) * 128 + nt * 16 + m16] = f2bf(o);
        }
    }
}

// ---- CSR build ----
__global__ __launch_bounds__(256) void hist_kernel(
    const int* __restrict__ dst, const int* __restrict__ et, int* __restrict__ counts)
{
    int e = blockIdx.x * 256 + threadIdx.x;
    atomicAdd(&counts[dst[e] * 3 + et[e]], 1);
}

// ROUND-2 VERBATIM single-block scan (passing)
__global__ __launch_bounds__(1024) void scan_kernel(
    const int* __restrict__ counts, int* __restrict__ row_ptr)
{
    __shared__ int sums[1024];
    const int t = threadIdx.x;
    const int CH = NSEG / 1024;   // 96
    int base = t * CH;
    int s = 0;
    for (int i = 0; i < CH; ++i) s += counts[base + i];
    sums[t] = s;
    __syncthreads();
    for (int off = 1; off < 1024; off <<= 1) {
        int v = sums[t];
        int add = (t >= off) ? sums[t - off] : 0;
        __syncthreads();
        sums[t] = v + add;
        __syncthreads();
    }
    int run = (t == 0) ? 0 : sums[t - 1];
    for (int i = 0; i < CH; ++i) { row_ptr[base + i] = run; run += counts[base + i]; }
    if (t == 1023) row_ptr[NSEG] = run;
}

__global__ __launch_bounds__(256) void scatter_kernel(
    const int* __restrict__ src, const int* __restrict__ dst, const int* __restrict__ et,
    const int* __restrict__ row_ptr, int* __restrict__ fill, int* __restrict__ edge_src)
{
    int e = blockIdx.x * 256 + threadIdx.x;
    int s = dst[e] * 3 + et[e];
    int pos = row_ptr[s] + atomicAdd(&fill[s], 1);
    edge_src[pos] = src[e];
}

// ---- per-(node,relation) mean aggregation over bf16 x (one wave/segment) ----
__global__ __launch_bounds__(256) void aggregate_kernel(
    const short* __restrict__ x, const int* __restrict__ row_ptr,
    const int* __restrict__ edge_src, short* __restrict__ agg)
{
    int seg  = blockIdx.x * 4 + (threadIdx.x >> 6);
    int lane = threadIdx.x & 63;
    int b = row_ptr[seg], e = row_ptr[seg + 1];
    int n = seg / 3, r = seg - n * 3;
    float ax = 0.f, ay = 0.f;
    int i = b;
    for (; i + 2 <= e; i += 2) {
        int s0 = edge_src[i], s1 = edge_src[i + 1];
        unsigned u0 = *(const unsigned*)(x + (size_t)s0 * 128 + lane * 2);
        unsigned u1 = *(const unsigned*)(x + (size_t)s1 * 128 + lane * 2);
        ax += bf2f((unsigned short)(u0 & 0xffff)) + bf2f((unsigned short)(u1 & 0xffff));
        ay += bf2f((unsigned short)(u0 >> 16))    + bf2f((unsigned short)(u1 >> 16));
    }
    if (i < e) {
        int s0 = edge_src[i];
        unsigned u0 = *(const unsigned*)(x + (size_t)s0 * 128 + lane * 2);
        ax += bf2f((unsigned short)(u0 & 0xffff));
        ay += bf2f((unsigned short)(u0 >> 16));
    }
    int cnt = e - b;
    float inv = 1.f / (float)(cnt > 0 ? cnt : 1);
    unsigned short lo = (unsigned short)f2bf(ax * inv);
    unsigned short hi = (unsigned short)f2bf(ay * inv);
    *(unsigned*)(agg + (size_t)n * 384 + r * 128 + lane * 2) = (unsigned)lo | ((unsigned)hi << 16);
}

// ---- classifier + masked CE loss (lm fp32, g bf16) ----
__global__ __launch_bounds__(256) void cls_loss_kernel(
    const float* __restrict__ lm, const short* __restrict__ g,
    const float* __restrict__ clsW, const float* __restrict__ clsb,
    const int* __restrict__ mask, const int* __restrict__ labels,
    float* __restrict__ logits, float* __restrict__ accb)
{
    __shared__ float W[2048];
    for (int i = threadIdx.x; i < 2048; i += 256) W[i] = clsW[i];
    __syncthreads();
    int n = blockIdx.x * 256 + threadIdx.x;
    float l[8];
    #pragma unroll
    for (int c = 0; c < 8; ++c) l[c] = clsb[c];
    const float* lmr = lm + (size_t)n * 128;
    const short* gr  = g  + (size_t)n * 128;
    #pragma unroll 4
    for (int h = 0; h < 128; h += 4) {
        float4 a = *(const float4*)(lmr + h);
        #pragma unroll
        for (int c = 0; c < 8; ++c) {
            const float* w = &W[c * 256 + h];
            l[c] = fmaf(a.x, w[0], l[c]); l[c] = fmaf(a.y, w[1], l[c]);
            l[c] = fmaf(a.z, w[2], l[c]); l[c] = fmaf(a.w, w[3], l[c]);
        }
    }
    #pragma unroll 2
    for (int h = 0; h < 128; h += 8) {
        uint4 raw = *(const uint4*)(gr + h);
        float a[8];
        a[0] = bf2f((unsigned short)(raw.x & 0xffff)); a[1] = bf2f((unsigned short)(raw.x >> 16));
        a[2] = bf2f((unsigned short)(raw.y & 0xffff)); a[3] = bf2f((unsigned short)(raw.y >> 16));
        a[4] = bf2f((unsigned short)(raw.z & 0xffff)); a[5] = bf2f((unsigned short)(raw.z >> 16));
        a[6] = bf2f((unsigned short)(raw.w & 0xffff)); a[7] = bf2f((unsigned short)(raw.w >> 16));
        #pragma unroll
        for (int c = 0; c < 8; ++c) {
            const float* w = &W[c * 256 + 128 + h];
            #pragma unroll
            for (int j = 0; j < 8; ++j) l[c] = fmaf(a[j], w[j], l[c]);
        }
    }
    #pragma unroll
    for (int c = 0; c < 8; ++c) logits[(size_t)n * 8 + c] = l[c];

    float m = l[0];
    #pragma unroll
    for (int c = 1; c < 8; ++c) m = fmaxf(m, l[c]);
    float ss = 0.f;
    #pragma unroll
    for (int c = 0; c < 8; ++c) ss += expf(l[c] - m);
    float lse = m + logf(ss);
    int y = labels[n];
    float ly = l[0];
    #pragma unroll
    for (int c = 1; c < 8; ++c) ly = (y == c) ? l[c] : ly;
    float nll = lse - ly;
    bool valid = (mask[n] == 1);
    float lv = valid ? nll : 0.f;
    float cv = valid ? 1.f : 0.f;
    #pragma unroll
    for (int off = 32; off > 0; off >>= 1) {
        lv += __shfl_down(lv, off, 64);
        cv += __shfl_down(cv, off, 64);
    }
    if ((threadIdx.x & 63) == 0) { atomicAdd(&accb[0], lv); atomicAdd(&accb[1], cv); }
}

__global__ void finalize_kernel(const float* __restrict__ accb, float* __restrict__ out)
{
    out[0] = accb[0] / fmaxf(accb[1], 1.f);
}

// ---- launcher ----
extern "C" void kernel_launch(void* const* d_in, const int* in_sizes, int n_in,
                              void* d_out, int out_size, void* d_ws, size_t ws_size,
                              hipStream_t stream)
{
    const float* output = (const float*)d_in[0];
    const int* edge_index = (const int*)d_in[1];
    const int* edge_type  = (const int*)d_in[2];
    const int* attn       = (const int*)d_in[3];
    const int* labels     = (const int*)d_in[4];
    const float* lmW   = (const float*)d_in[5];
    const float* lmb   = (const float*)d_in[6];
    const float* lng   = (const float*)d_in[7];
    const float* lnb   = (const float*)d_in[8];
    const float* Wrel  = (const float*)d_in[9];
    const float* Wroot = (const float*)d_in[10];
    const float* convb = (const float*)d_in[11];
    const float* clsW  = (const float*)d_in[12];
    const float* clsb  = (const float*)d_in[13];

    char* ws = (char*)d_ws;
    float* lm_f32 = (float*)ws;                          ws += (size_t)Nn * Dd * 4;
    short* lm_bf  = (short*)ws;                          ws += (size_t)Nn * Dd * 2;
    short* x1_bf  = (short*)ws;                          ws += (size_t)Nn * Dd * 2;
    short* x2_bf  = (short*)ws;                          ws += (size_t)Nn * Dd * 2;
    short* agg_bf = (short*)ws;                          ws += (size_t)Nn * 384 * 2;
    short* Wp_all = (short*)ws;                          ws += (size_t)262144 * 2;
    // zeroed region: [accb | counts | fill] contiguous
    float* accb   = (float*)ws;                          ws += 64;
    int* counts   = (int*)ws;                            ws += (size_t)NSEG * 4;
    int* fill     = (int*)ws;                            ws += (size_t)NSEG * 4;
    int* row_ptr  = (int*)ws;                            ws += (size_t)(NSEG + 4) * 4;
    int* edge_src = (int*)ws;

    short* Wp_lm = Wp_all;
    short* Wp_c0 = Wp_all + 131072;
    short* Wp_c1 = Wp_all + 131072 + 65536;

    const int* e_src = edge_index;
    const int* e_dst = edge_index + Ee;

    hipMemsetAsync(accb, 0, 64 + 2 * (size_t)NSEG * 4, stream);

    pack_all_kernel<<<dim3(1024), dim3(256), 0, stream>>>(lmW, Wrel, Wroot, Wp_all);

    // LM head + ReLU + fused LN
    lm_gemm_ln_kernel<<<dim3(Nn / 64), dim3(256), 0, stream>>>(
        output, Wp_lm, lmb, lng, lnb, lm_f32, lm_bf);

    // CSR over (dst, relation)
    hist_kernel<<<dim3(Ee / 256), dim3(256), 0, stream>>>(e_dst, edge_type, counts);
    scan_kernel<<<dim3(1), dim3(1024), 0, stream>>>(counts, row_ptr);
    scatter_kernel<<<dim3(Ee / 256), dim3(256), 0, stream>>>(
        e_src, e_dst, edge_type, row_ptr, fill, edge_src);

    // RGCN layers
    aggregate_kernel<<<dim3(NSEG / 4), dim3(256), 0, stream>>>(lm_bf, row_ptr, edge_src, agg_bf);
    conv_gemm_kernel<<<dim3(Nn / 64), dim3(256), 0, stream>>>(
        agg_bf, lm_bf, Wp_c0, convb, x1_bf);
    aggregate_kernel<<<dim3(NSEG / 4), dim3(256), 0, stream>>>(x1_bf, row_ptr, edge_src, agg_bf);
    conv_gemm_kernel<<<dim3(Nn / 64), dim3(256), 0, stream>>>(
        agg_bf, x1_bf, Wp_c1, convb + Dd, x2_bf);

    // classifier + loss
    float* logits = (float*)d_out + 1;
    cls_loss_kernel<<<dim3(Nn / 256), dim3(256), 0, stream>>>(
        lm_f32, x2_bf, clsW, clsb, attn, labels, logits, accb);
    finalize_kernel<<<dim3(1), dim3(1), 0, stream>>>(accb, (float*)d_out);
}

// Round 6
// 455.595 us; speedup vs baseline: 1.5453x; 1.0707x over previous
//
#include <hip/hip_runtime.h>

#define Bb 32
#define Ll 1024
#define LMD 1024
#define Dd 128
#define Rr 3
#define NLAYER 2
#define Cc 8
#define Nn (Bb*Ll)          // 32768
#define Ee 524288
#define NSEG (Nn*Rr)        // 98304
#define LN_EPS 1e-5f

typedef __attribute__((ext_vector_type(8))) short bf16x8;
typedef __attribute__((ext_vector_type(4))) float f32x4;

__device__ inline short f2bf(float f) {
    unsigned u = __builtin_bit_cast(unsigned, f);
    u += 0x7fff + ((u >> 16) & 1);           // RNE
    return (short)(u >> 16);
}
__device__ inline float bf2f(unsigned short s) {
    unsigned u = ((unsigned)s) << 16;
    return __builtin_bit_cast(float, u);
}

// ---- one pack kernel for all weights (round-4 verbatim) ----
__global__ __launch_bounds__(256) void pack_all_kernel(
    const float* __restrict__ lmW, const float* __restrict__ Wrel,
    const float* __restrict__ Wroot, short* __restrict__ Wp_all)
{
    int idx = blockIdx.x * 256 + threadIdx.x;   // 0..262143
    float v;
    if (idx < 131072) {
        int kk = idx & 31, n = (idx >> 5) & 127, ks = idx >> 12;
        v = lmW[n * 1024 + ks * 32 + kk];
    } else {
        int j = idx - 131072;
        int layer = j >> 16;
        int kk = j & 31, n = (j >> 5) & 127, ks = (j >> 12) & 15;
        int k = ks * 32 + kk;
        v = (k < 384) ? Wrel[(size_t)layer * 49152 + (size_t)k * 128 + n]
                      : Wroot[(size_t)layer * 16384 + (size_t)(k - 384) * 128 + n];
    }
    Wp_all[idx] = f2bf(v);
}

// ---- LM head GEMM (MFMA bf16) + bias + ReLU + fused LayerNorm ----
// ROUND-2/4 VERBATIM (passing, no split-K). 512 blocks x 256 thr.
__global__ __launch_bounds__(256) void lm_gemm_ln_kernel(
    const float* __restrict__ A,        // [M,1024] fp32
    const short* __restrict__ Wp,       // [32][128][32] bf16 frag-packed
    const float* __restrict__ bias,     // [128]
    const float* __restrict__ lng, const float* __restrict__ lnb,
    float* __restrict__ lm_f32, short* __restrict__ lm_bf16)
{
    const int wv   = threadIdx.x >> 6;
    const int lane = threadIdx.x & 63;
    const int m16  = lane & 15;
    const int quad = lane >> 4;
    const int row_frag = blockIdx.x * 64 + wv * 16 + m16;
    const float* arow = A + (size_t)row_frag * 1024 + quad * 8;

    f32x4 acc[8];
    #pragma unroll
    for (int i = 0; i < 8; ++i) acc[i] = (f32x4){0.f, 0.f, 0.f, 0.f};

    #pragma unroll 2
    for (int ks = 0; ks < 32; ++ks) {
        const short* wpb = Wp + ks * 4096 + m16 * 32 + quad * 8;
        bf16x8 bfr[8];
        #pragma unroll
        for (int nt = 0; nt < 8; ++nt)
            bfr[nt] = *(const bf16x8*)(wpb + nt * 512);
        const float4* ap = (const float4*)(arow + ks * 32);
        float4 a0 = ap[0], a1 = ap[1];
        union { bf16x8 v; short s[8]; } af;
        af.s[0] = f2bf(a0.x); af.s[1] = f2bf(a0.y);
        af.s[2] = f2bf(a0.z); af.s[3] = f2bf(a0.w);
        af.s[4] = f2bf(a1.x); af.s[5] = f2bf(a1.y);
        af.s[6] = f2bf(a1.z); af.s[7] = f2bf(a1.w);
        #pragma unroll
        for (int nt = 0; nt < 8; ++nt)
            acc[nt] = __builtin_amdgcn_mfma_f32_16x16x32_bf16(af.v, bfr[nt], acc[nt], 0, 0, 0);
    }

    float v[8][4];
    #pragma unroll
    for (int nt = 0; nt < 8; ++nt) {
        float bs = bias[nt * 16 + m16];
        #pragma unroll
        for (int r = 0; r < 4; ++r) v[nt][r] = fmaxf(acc[nt][r] + bs, 0.f);
    }
    float gv[8], bv[8];
    #pragma unroll
    for (int nt = 0; nt < 8; ++nt) { gv[nt] = lng[nt * 16 + m16]; bv[nt] = lnb[nt * 16 + m16]; }

    const int row0 = blockIdx.x * 64 + wv * 16 + quad * 4;
    #pragma unroll
    for (int r = 0; r < 4; ++r) {
        float s = 0.f;
        #pragma unroll
        for (int nt = 0; nt < 8; ++nt) s += v[nt][r];
        s += __shfl_xor(s, 1, 64); s += __shfl_xor(s, 2, 64);
        s += __shfl_xor(s, 4, 64); s += __shfl_xor(s, 8, 64);
        float mu = s * (1.f / 128.f);
        float q = 0.f;
        #pragma unroll
        for (int nt = 0; nt < 8; ++nt) { float d = v[nt][r] - mu; q += d * d; }
        q += __shfl_xor(q, 1, 64); q += __shfl_xor(q, 2, 64);
        q += __shfl_xor(q, 4, 64); q += __shfl_xor(q, 8, 64);
        float rs = rsqrtf(q * (1.f / 128.f) + LN_EPS);
        size_t rowoff = (size_t)(row0 + r) * 128;
        #pragma unroll
        for (int nt = 0; nt < 8; ++nt) {
            float o = (v[nt][r] - mu) * rs * gv[nt] + bv[nt];
            lm_f32[rowoff + nt * 16 + m16] = o;
            lm_bf16[rowoff + nt * 16 + m16] = f2bf(o);
        }
    }
}

// ---- conv GEMM (MFMA bf16): out = relu([agg|x] * Wc + bias), K=512 ----
__global__ __launch_bounds__(256) void conv_gemm_kernel(
    const short* __restrict__ A1,       // [N,384] bf16 (agg)
    const short* __restrict__ A2,       // [N,128] bf16 (x)
    const short* __restrict__ Wp,       // [16][128][32] bf16 frag-packed
    const float* __restrict__ bias,
    short* __restrict__ out_bf16)       // [N,128]
{
    const int wv   = threadIdx.x >> 6;
    const int lane = threadIdx.x & 63;
    const int m16  = lane & 15;
    const int quad = lane >> 4;
    const int row_frag = blockIdx.x * 64 + wv * 16 + m16;
    const short* a1row = A1 + (size_t)row_frag * 384 + quad * 8;
    const short* a2row = A2 + (size_t)row_frag * 128 + quad * 8;

    f32x4 acc[8];
    #pragma unroll
    for (int i = 0; i < 8; ++i) acc[i] = (f32x4){0.f, 0.f, 0.f, 0.f};

    #pragma unroll 2
    for (int ks = 0; ks < 16; ++ks) {
        const short* wpb = Wp + ks * 4096 + m16 * 32 + quad * 8;
        bf16x8 bfr[8];
        #pragma unroll
        for (int nt = 0; nt < 8; ++nt)
            bfr[nt] = *(const bf16x8*)(wpb + nt * 512);
        const short* ar = (ks < 12) ? (a1row + ks * 32) : (a2row + (ks - 12) * 32);
        bf16x8 af = *(const bf16x8*)ar;
        #pragma unroll
        for (int nt = 0; nt < 8; ++nt)
            acc[nt] = __builtin_amdgcn_mfma_f32_16x16x32_bf16(af, bfr[nt], acc[nt], 0, 0, 0);
    }

    const int row0 = blockIdx.x * 64 + wv * 16 + quad * 4;
    #pragma unroll
    for (int nt = 0; nt < 8; ++nt) {
        float bs = bias[nt * 16 + m16];
        #pragma unroll
        for (int r = 0; r < 4; ++r) {
            float o = fmaxf(acc[nt][r] + bs, 0.f);
            out_bf16[(size_t)(row0 + r) * 128 + nt * 16 + m16] = f2bf(o);
        }
    }
}

// ---- CSR build ----
__global__ __launch_bounds__(256) void hist_kernel(
    const int* __restrict__ dst, const int* __restrict__ et, int* __restrict__ counts)
{
    int e = blockIdx.x * 256 + threadIdx.x;
    atomicAdd(&counts[dst[e] * 3 + et[e]], 1);
}

// hierarchical scan (THE round-6 experiment): coalesced, parallel
__global__ __launch_bounds__(256) void scan_blk_kernel(
    const int* __restrict__ counts, int* __restrict__ excl, int* __restrict__ blksum)
{
    __shared__ int wsum[4];
    int t = threadIdx.x, lane = t & 63, wv = t >> 6;
    int g = blockIdx.x * 256 + t;
    int v = counts[g];
    int x = v;
    #pragma unroll
    for (int off = 1; off < 64; off <<= 1) {
        int y = __shfl_up(x, off, 64);
        if (lane >= off) x += y;
    }
    if (lane == 63) wsum[wv] = x;
    __syncthreads();
    int woff = 0;
    for (int i = 0; i < wv; ++i) woff += wsum[i];
    excl[g] = woff + x - v;
    if (t == 255) blksum[blockIdx.x] = woff + x;
}

__global__ __launch_bounds__(512) void scan_top_kernel(
    const int* __restrict__ blksum, int* __restrict__ blkoff)
{
    __shared__ int wsum[8];
    int t = threadIdx.x, lane = t & 63, wv = t >> 6;
    int v = (t < 384) ? blksum[t] : 0;
    int x = v;
    #pragma unroll
    for (int off = 1; off < 64; off <<= 1) {
        int y = __shfl_up(x, off, 64);
        if (lane >= off) x += y;
    }
    if (lane == 63) wsum[wv] = x;
    __syncthreads();
    int woff = 0;
    for (int i = 0; i < wv; ++i) woff += wsum[i];
    if (t < 384) blkoff[t] = woff + x - v;
}

__global__ __launch_bounds__(256) void scan_add_kernel(
    const int* __restrict__ excl, const int* __restrict__ blkoff, int* __restrict__ row_ptr)
{
    int g = blockIdx.x * 256 + threadIdx.x;
    row_ptr[g] = excl[g] + blkoff[blockIdx.x];
    if (g == 0) row_ptr[NSEG] = Ee;
}

__global__ __launch_bounds__(256) void scatter_kernel(
    const int* __restrict__ src, const int* __restrict__ dst, const int* __restrict__ et,
    const int* __restrict__ row_ptr, int* __restrict__ fill, int* __restrict__ edge_src)
{
    int e = blockIdx.x * 256 + threadIdx.x;
    int s = dst[e] * 3 + et[e];
    int pos = row_ptr[s] + atomicAdd(&fill[s], 1);
    edge_src[pos] = src[e];
}

// ---- per-(node,relation) mean aggregation over bf16 x (one wave/segment) ----
__global__ __launch_bounds__(256) void aggregate_kernel(
    const short* __restrict__ x, const int* __restrict__ row_ptr,
    const int* __restrict__ edge_src, short* __restrict__ agg)
{
    int seg  = blockIdx.x * 4 + (threadIdx.x >> 6);
    int lane = threadIdx.x & 63;
    int b = row_ptr[seg], e = row_ptr[seg + 1];
    int n = seg / 3, r = seg - n * 3;
    float ax = 0.f, ay = 0.f;
    int i = b;
    for (; i + 2 <= e; i += 2) {
        int s0 = edge_src[i], s1 = edge_src[i + 1];
        unsigned u0 = *(const unsigned*)(x + (size_t)s0 * 128 + lane * 2);
        unsigned u1 = *(const unsigned*)(x + (size_t)s1 * 128 + lane * 2);
        ax += bf2f((unsigned short)(u0 & 0xffff)) + bf2f((unsigned short)(u1 & 0xffff));
        ay += bf2f((unsigned short)(u0 >> 16))    + bf2f((unsigned short)(u1 >> 16));
    }
    if (i < e) {
        int s0 = edge_src[i];
        unsigned u0 = *(const unsigned*)(x + (size_t)s0 * 128 + lane * 2);
        ax += bf2f((unsigned short)(u0 & 0xffff));
        ay += bf2f((unsigned short)(u0 >> 16));
    }
    int cnt = e - b;
    float inv = 1.f / (float)(cnt > 0 ? cnt : 1);
    unsigned short lo = (unsigned short)f2bf(ax * inv);
    unsigned short hi = (unsigned short)f2bf(ay * inv);
    *(unsigned*)(agg + (size_t)n * 384 + r * 128 + lane * 2) = (unsigned)lo | ((unsigned)hi << 16);
}

// ---- classifier + masked CE loss (lm fp32, g bf16) ----
__global__ __launch_bounds__(256) void cls_loss_kernel(
    const float* __restrict__ lm, const short* __restrict__ g,
    const float* __restrict__ clsW, const float* __restrict__ clsb,
    const int* __restrict__ mask, const int* __restrict__ labels,
    float* __restrict__ logits, float* __restrict__ accb)
{
    __shared__ float W[2048];
    for (int i = threadIdx.x; i < 2048; i += 256) W[i] = clsW[i];
    __syncthreads();
    int n = blockIdx.x * 256 + threadIdx.x;
    float l[8];
    #pragma unroll
    for (int c = 0; c < 8; ++c) l[c] = clsb[c];
    const float* lmr = lm + (size_t)n * 128;
    const short* gr  = g  + (size_t)n * 128;
    #pragma unroll 4
    for (int h = 0; h < 128; h += 4) {
        float4 a = *(const float4*)(lmr + h);
        #pragma unroll
        for (int c = 0; c < 8; ++c) {
            const float* w = &W[c * 256 + h];
            l[c] = fmaf(a.x, w[0], l[c]); l[c] = fmaf(a.y, w[1], l[c]);
            l[c] = fmaf(a.z, w[2], l[c]); l[c] = fmaf(a.w, w[3], l[c]);
        }
    }
    #pragma unroll 2
    for (int h = 0; h < 128; h += 8) {
        uint4 raw = *(const uint4*)(gr + h);
        float a[8];
        a[0] = bf2f((unsigned short)(raw.x & 0xffff)); a[1] = bf2f((unsigned short)(raw.x >> 16));
        a[2] = bf2f((unsigned short)(raw.y & 0xffff)); a[3] = bf2f((unsigned short)(raw.y >> 16));
        a[4] = bf2f((unsigned short)(raw.z & 0xffff)); a[5] = bf2f((unsigned short)(raw.z >> 16));
        a[6] = bf2f((unsigned short)(raw.w & 0xffff)); a[7] = bf2f((unsigned short)(raw.w >> 16));
        #pragma unroll
        for (int c = 0; c < 8; ++c) {
            const float* w = &W[c * 256 + 128 + h];
            #pragma unroll
            for (int j = 0; j < 8; ++j) l[c] = fmaf(a[j], w[j], l[c]);
        }
    }
    #pragma unroll
    for (int c = 0; c < 8; ++c) logits[(size_t)n * 8 + c] = l[c];

    float m = l[0];
    #pragma unroll
    for (int c = 1; c < 8; ++c) m = fmaxf(m, l[c]);
    float ss = 0.f;
    #pragma unroll
    for (int c = 0; c < 8; ++c) ss += expf(l[c] - m);
    float lse = m + logf(ss);
    int y = labels[n];
    float ly = l[0];
    #pragma unroll
    for (int c = 1; c < 8; ++c) ly = (y == c) ? l[c] : ly;
    float nll = lse - ly;
    bool valid = (mask[n] == 1);
    float lv = valid ? nll : 0.f;
    float cv = valid ? 1.f : 0.f;
    #pragma unroll
    for (int off = 32; off > 0; off >>= 1) {
        lv += __shfl_down(lv, off, 64);
        cv += __shfl_down(cv, off, 64);
    }
    if ((threadIdx.x & 63) == 0) { atomicAdd(&accb[0], lv); atomicAdd(&accb[1], cv); }
}

__global__ void finalize_kernel(const float* __restrict__ accb, float* __restrict__ out)
{
    out[0] = accb[0] / fmaxf(accb[1], 1.f);
}

// ---- launcher ----
extern "C" void kernel_launch(void* const* d_in, const int* in_sizes, int n_in,
                              void* d_out, int out_size, void* d_ws, size_t ws_size,
                              hipStream_t stream)
{
    const float* output = (const float*)d_in[0];
    const int* edge_index = (const int*)d_in[1];
    const int* edge_type  = (const int*)d_in[2];
    const int* attn       = (const int*)d_in[3];
    const int* labels     = (const int*)d_in[4];
    const float* lmW   = (const float*)d_in[5];
    const float* lmb   = (const float*)d_in[6];
    const float* lng   = (const float*)d_in[7];
    const float* lnb   = (const float*)d_in[8];
    const float* Wrel  = (const float*)d_in[9];
    const float* Wroot = (const float*)d_in[10];
    const float* convb = (const float*)d_in[11];
    const float* clsW  = (const float*)d_in[12];
    const float* clsb  = (const float*)d_in[13];

    char* ws = (char*)d_ws;
    float* lm_f32 = (float*)ws;                          ws += (size_t)Nn * Dd * 4;
    short* lm_bf  = (short*)ws;                          ws += (size_t)Nn * Dd * 2;
    short* x1_bf  = (short*)ws;                          ws += (size_t)Nn * Dd * 2;
    short* x2_bf  = (short*)ws;                          ws += (size_t)Nn * Dd * 2;
    short* agg_bf = (short*)ws;                          ws += (size_t)Nn * 384 * 2;
    short* Wp_all = (short*)ws;                          ws += (size_t)262144 * 2;
    // zeroed region: [accb | counts | fill] contiguous (memset, round-4 form)
    float* accb   = (float*)ws;                          ws += 64;
    int* counts   = (int*)ws;                            ws += (size_t)NSEG * 4;
    int* fill     = (int*)ws;                            ws += (size_t)NSEG * 4;
    int* row_ptr  = (int*)ws;                            ws += (size_t)(NSEG + 4) * 4;
    int* excl     = (int*)ws;                            ws += (size_t)NSEG * 4;
    int* blksum   = (int*)ws;                            ws += 512 * 4;
    int* blkoff   = (int*)ws;                            ws += 512 * 4;
    int* edge_src = (int*)ws;

    short* Wp_lm = Wp_all;
    short* Wp_c0 = Wp_all + 131072;
    short* Wp_c1 = Wp_all + 131072 + 65536;

    const int* e_src = edge_index;
    const int* e_dst = edge_index + Ee;

    hipMemsetAsync(accb, 0, 64 + 2 * (size_t)NSEG * 4, stream);

    pack_all_kernel<<<dim3(1024), dim3(256), 0, stream>>>(lmW, Wrel, Wroot, Wp_all);

    // LM head + ReLU + fused LN (known-good 256-thr version)
    lm_gemm_ln_kernel<<<dim3(Nn / 64), dim3(256), 0, stream>>>(
        output, Wp_lm, lmb, lng, lnb, lm_f32, lm_bf);

    // CSR over (dst, relation) — hierarchical scan experiment
    hist_kernel<<<dim3(Ee / 256), dim3(256), 0, stream>>>(e_dst, edge_type, counts);
    scan_blk_kernel<<<dim3(NSEG / 256), dim3(256), 0, stream>>>(counts, excl, blksum);
    scan_top_kernel<<<dim3(1), dim3(512), 0, stream>>>(blksum, blkoff);
    scan_add_kernel<<<dim3(NSEG / 256), dim3(256), 0, stream>>>(excl, blkoff, row_ptr);
    scatter_kernel<<<dim3(Ee / 256), dim3(256), 0, stream>>>(
        e_src, e_dst, edge_type, row_ptr, fill, edge_src);

    // RGCN layers
    aggregate_kernel<<<dim3(NSEG / 4), dim3(256), 0, stream>>>(lm_bf, row_ptr, edge_src, agg_bf);
    conv_gemm_kernel<<<dim3(Nn / 64), dim3(256), 0, stream>>>(
        agg_bf, lm_bf, Wp_c0, convb, x1_bf);
    aggregate_kernel<<<dim3(NSEG / 4), dim3(256), 0, stream>>>(x1_bf, row_ptr, edge_src, agg_bf);
    conv_gemm_kernel<<<dim3(Nn / 64), dim3(256), 0, stream>>>(
        agg_bf, x1_bf, Wp_c1, convb + Dd, x2_bf);

    // classifier + loss
    float* logits = (float*)d_out + 1;
    cls_loss_kernel<<<dim3(Nn / 256), dim3(256), 0, stream>>>(
        lm_f32, x2_bf, clsW, clsb, attn, labels, logits, accb);
    finalize_kernel<<<dim3(1), dim3(1), 0, stream>>>(accb, (float*)d_out);
}

// Round 7
// 438.452 us; speedup vs baseline: 1.6057x; 1.0391x over previous
//
#include <hip/hip_runtime.h>

#define Bb 32
#define Ll 1024
#define LMD 1024
#define Dd 128
#define Rr 3
#define NLAYER 2
#define Cc 8
#define Nn (Bb*Ll)          // 32768
#define Ee 524288
#define NSEG (Nn*Rr)        // 98304
#define LN_EPS 1e-5f

typedef __attribute__((ext_vector_type(8))) short bf16x8;
typedef __attribute__((ext_vector_type(4))) float f32x4;

__device__ inline short f2bf(float f) {
    unsigned u = __builtin_bit_cast(unsigned, f);
    u += 0x7fff + ((u >> 16) & 1);           // RNE
    return (short)(u >> 16);
}
__device__ inline float bf2f(unsigned short s) {
    unsigned u = ((unsigned)s) << 16;
    return __builtin_bit_cast(float, u);
}

// ---- prep: weight pack (blocks 0..1023, verbatim r4/r6 math) + edge histogram
// (blocks 1024..3071, verbatim r6 hist). counts pre-zeroed by memset.
__global__ __launch_bounds__(256) void prep_kernel(
    const float* __restrict__ lmW, const float* __restrict__ Wrel,
    const float* __restrict__ Wroot, short* __restrict__ Wp_all,
    const int* __restrict__ dst, const int* __restrict__ et,
    int* __restrict__ counts)
{
    int bid = blockIdx.x;
    if (bid < 1024) {
        int idx = bid * 256 + threadIdx.x;   // 0..262143
        float v;
        if (idx < 131072) {
            int kk = idx & 31, n = (idx >> 5) & 127, ks = idx >> 12;
            v = lmW[n * 1024 + ks * 32 + kk];
        } else {
            int j = idx - 131072;
            int layer = j >> 16;
            int kk = j & 31, n = (j >> 5) & 127, ks = (j >> 12) & 15;
            int k = ks * 32 + kk;
            v = (k < 384) ? Wrel[(size_t)layer * 49152 + (size_t)k * 128 + n]
                          : Wroot[(size_t)layer * 16384 + (size_t)(k - 384) * 128 + n];
        }
        Wp_all[idx] = f2bf(v);
    } else {
        int e = (bid - 1024) * 256 + threadIdx.x;   // 0..Ee-1
        atomicAdd(&counts[dst[e] * 3 + et[e]], 1);
    }
}

// ---- LM head GEMM (MFMA bf16) + bias + ReLU + fused LayerNorm ----
// Known-good r2/r4/r6 structure; only change: lm_f32 store removed.
__global__ __launch_bounds__(256) void lm_gemm_ln_kernel(
    const float* __restrict__ A,        // [M,1024] fp32
    const short* __restrict__ Wp,       // [32][128][32] bf16 frag-packed
    const float* __restrict__ bias,     // [128]
    const float* __restrict__ lng, const float* __restrict__ lnb,
    short* __restrict__ lm_bf16)
{
    const int wv   = threadIdx.x >> 6;
    const int lane = threadIdx.x & 63;
    const int m16  = lane & 15;
    const int quad = lane >> 4;
    const int row_frag = blockIdx.x * 64 + wv * 16 + m16;
    const float* arow = A + (size_t)row_frag * 1024 + quad * 8;

    f32x4 acc[8];
    #pragma unroll
    for (int i = 0; i < 8; ++i) acc[i] = (f32x4){0.f, 0.f, 0.f, 0.f};

    #pragma unroll 2
    for (int ks = 0; ks < 32; ++ks) {
        const short* wpb = Wp + ks * 4096 + m16 * 32 + quad * 8;
        bf16x8 bfr[8];
        #pragma unroll
        for (int nt = 0; nt < 8; ++nt)
            bfr[nt] = *(const bf16x8*)(wpb + nt * 512);
        const float4* ap = (const float4*)(arow + ks * 32);
        float4 a0 = ap[0], a1 = ap[1];
        union { bf16x8 v; short s[8]; } af;
        af.s[0] = f2bf(a0.x); af.s[1] = f2bf(a0.y);
        af.s[2] = f2bf(a0.z); af.s[3] = f2bf(a0.w);
        af.s[4] = f2bf(a1.x); af.s[5] = f2bf(a1.y);
        af.s[6] = f2bf(a1.z); af.s[7] = f2bf(a1.w);
        #pragma unroll
        for (int nt = 0; nt < 8; ++nt)
            acc[nt] = __builtin_amdgcn_mfma_f32_16x16x32_bf16(af.v, bfr[nt], acc[nt], 0, 0, 0);
    }

    float v[8][4];
    #pragma unroll
    for (int nt = 0; nt < 8; ++nt) {
        float bs = bias[nt * 16 + m16];
        #pragma unroll
        for (int r = 0; r < 4; ++r) v[nt][r] = fmaxf(acc[nt][r] + bs, 0.f);
    }
    float gv[8], bv[8];
    #pragma unroll
    for (int nt = 0; nt < 8; ++nt) { gv[nt] = lng[nt * 16 + m16]; bv[nt] = lnb[nt * 16 + m16]; }

    const int row0 = blockIdx.x * 64 + wv * 16 + quad * 4;
    #pragma unroll
    for (int r = 0; r < 4; ++r) {
        float s = 0.f;
        #pragma unroll
        for (int nt = 0; nt < 8; ++nt) s += v[nt][r];
        s += __shfl_xor(s, 1, 64); s += __shfl_xor(s, 2, 64);
        s += __shfl_xor(s, 4, 64); s += __shfl_xor(s, 8, 64);
        float mu = s * (1.f / 128.f);
        float q = 0.f;
        #pragma unroll
        for (int nt = 0; nt < 8; ++nt) { float d = v[nt][r] - mu; q += d * d; }
        q += __shfl_xor(q, 1, 64); q += __shfl_xor(q, 2, 64);
        q += __shfl_xor(q, 4, 64); q += __shfl_xor(q, 8, 64);
        float rs = rsqrtf(q * (1.f / 128.f) + LN_EPS);
        size_t rowoff = (size_t)(row0 + r) * 128;
        #pragma unroll
        for (int nt = 0; nt < 8; ++nt) {
            float o = (v[nt][r] - mu) * rs * gv[nt] + bv[nt];
            lm_bf16[rowoff + nt * 16 + m16] = f2bf(o);
        }
    }
}

// ---- conv GEMM (MFMA bf16): out = relu([agg|x] * Wc + bias), K=512 ----
__global__ __launch_bounds__(256) void conv_gemm_kernel(
    const short* __restrict__ A1,       // [N,384] bf16 (agg)
    const short* __restrict__ A2,       // [N,128] bf16 (x)
    const short* __restrict__ Wp,       // [16][128][32] bf16 frag-packed
    const float* __restrict__ bias,
    short* __restrict__ out_bf16)       // [N,128]
{
    const int wv   = threadIdx.x >> 6;
    const int lane = threadIdx.x & 63;
    const int m16  = lane & 15;
    const int quad = lane >> 4;
    const int row_frag = blockIdx.x * 64 + wv * 16 + m16;
    const short* a1row = A1 + (size_t)row_frag * 384 + quad * 8;
    const short* a2row = A2 + (size_t)row_frag * 128 + quad * 8;

    f32x4 acc[8];
    #pragma unroll
    for (int i = 0; i < 8; ++i) acc[i] = (f32x4){0.f, 0.f, 0.f, 0.f};

    #pragma unroll 2
    for (int ks = 0; ks < 16; ++ks) {
        const short* wpb = Wp + ks * 4096 + m16 * 32 + quad * 8;
        bf16x8 bfr[8];
        #pragma unroll
        for (int nt = 0; nt < 8; ++nt)
            bfr[nt] = *(const bf16x8*)(wpb + nt * 512);
        const short* ar = (ks < 12) ? (a1row + ks * 32) : (a2row + (ks - 12) * 32);
        bf16x8 af = *(const bf16x8*)ar;
        #pragma unroll
        for (int nt = 0; nt < 8; ++nt)
            acc[nt] = __builtin_amdgcn_mfma_f32_16x16x32_bf16(af, bfr[nt], acc[nt], 0, 0, 0);
    }

    const int row0 = blockIdx.x * 64 + wv * 16 + quad * 4;
    #pragma unroll
    for (int nt = 0; nt < 8; ++nt) {
        float bs = bias[nt * 16 + m16];
        #pragma unroll
        for (int r = 0; r < 4; ++r) {
            float o = fmaxf(acc[nt][r] + bs, 0.f);
            out_bf16[(size_t)(row0 + r) * 128 + nt * 16 + m16] = f2bf(o);
        }
    }
}

// ---- CSR scan (hierarchical, r6-verified) ----
__global__ __launch_bounds__(256) void scan_blk_kernel(
    const int* __restrict__ counts, int* __restrict__ excl, int* __restrict__ blksum)
{
    __shared__ int wsum[4];
    int t = threadIdx.x, lane = t & 63, wv = t >> 6;
    int g = blockIdx.x * 256 + t;
    int v = counts[g];
    int x = v;
    #pragma unroll
    for (int off = 1; off < 64; off <<= 1) {
        int y = __shfl_up(x, off, 64);
        if (lane >= off) x += y;
    }
    if (lane == 63) wsum[wv] = x;
    __syncthreads();
    int woff = 0;
    for (int i = 0; i < wv; ++i) woff += wsum[i];
    excl[g] = woff + x - v;
    if (t == 255) blksum[blockIdx.x] = woff + x;
}

// scan_add with fused top-level: each block computes sum(blksum[j<bid]) itself.
__global__ __launch_bounds__(256) void scan_add_kernel(
    const int* __restrict__ excl, const int* __restrict__ blksum,
    int* __restrict__ row_ptr)
{
    __shared__ int ws4[4];
    __shared__ int off_sh;
    const int t = threadIdx.x, bid = blockIdx.x;
    int s = 0;
    for (int j = t; j < bid; j += 256) s += blksum[j];   // bid<384: <=2 iters
    #pragma unroll
    for (int o = 32; o > 0; o >>= 1) s += __shfl_xor(s, o, 64);
    if ((t & 63) == 0) ws4[t >> 6] = s;
    __syncthreads();
    if (t == 0) off_sh = ws4[0] + ws4[1] + ws4[2] + ws4[3];
    __syncthreads();
    int g = bid * 256 + t;
    row_ptr[g] = excl[g] + off_sh;
    if (g == 0) row_ptr[NSEG] = Ee;
}

__global__ __launch_bounds__(256) void scatter_kernel(
    const int* __restrict__ src, const int* __restrict__ dst, const int* __restrict__ et,
    const int* __restrict__ row_ptr, int* __restrict__ fill, int* __restrict__ edge_src)
{
    int e = blockIdx.x * 256 + threadIdx.x;
    int s = dst[e] * 3 + et[e];
    int pos = row_ptr[s] + atomicAdd(&fill[s], 1);
    edge_src[pos] = src[e];
}

// ---- per-(node,relation) mean aggregation over bf16 x (one wave/segment) ----
__global__ __launch_bounds__(256) void aggregate_kernel(
    const short* __restrict__ x, const int* __restrict__ row_ptr,
    const int* __restrict__ edge_src, short* __restrict__ agg)
{
    int seg  = blockIdx.x * 4 + (threadIdx.x >> 6);
    int lane = threadIdx.x & 63;
    int b = row_ptr[seg], e = row_ptr[seg + 1];
    int n = seg / 3, r = seg - n * 3;
    float ax = 0.f, ay = 0.f;
    int i = b;
    for (; i + 4 <= e; i += 4) {
        int s0 = edge_src[i],     s1 = edge_src[i + 1];
        int s2 = edge_src[i + 2], s3 = edge_src[i + 3];
        unsigned u0 = *(const unsigned*)(x + (size_t)s0 * 128 + lane * 2);
        unsigned u1 = *(const unsigned*)(x + (size_t)s1 * 128 + lane * 2);
        unsigned u2 = *(const unsigned*)(x + (size_t)s2 * 128 + lane * 2);
        unsigned u3 = *(const unsigned*)(x + (size_t)s3 * 128 + lane * 2);
        ax += bf2f((unsigned short)(u0 & 0xffff)) + bf2f((unsigned short)(u1 & 0xffff))
            + bf2f((unsigned short)(u2 & 0xffff)) + bf2f((unsigned short)(u3 & 0xffff));
        ay += bf2f((unsigned short)(u0 >> 16)) + bf2f((unsigned short)(u1 >> 16))
            + bf2f((unsigned short)(u2 >> 16)) + bf2f((unsigned short)(u3 >> 16));
    }
    for (; i + 2 <= e; i += 2) {
        int s0 = edge_src[i], s1 = edge_src[i + 1];
        unsigned u0 = *(const unsigned*)(x + (size_t)s0 * 128 + lane * 2);
        unsigned u1 = *(const unsigned*)(x + (size_t)s1 * 128 + lane * 2);
        ax += bf2f((unsigned short)(u0 & 0xffff)) + bf2f((unsigned short)(u1 & 0xffff));
        ay += bf2f((unsigned short)(u0 >> 16))    + bf2f((unsigned short)(u1 >> 16));
    }
    if (i < e) {
        int s0 = edge_src[i];
        unsigned u0 = *(const unsigned*)(x + (size_t)s0 * 128 + lane * 2);
        ax += bf2f((unsigned short)(u0 & 0xffff));
        ay += bf2f((unsigned short)(u0 >> 16));
    }
    int cnt = e - b;
    float inv = 1.f / (float)(cnt > 0 ? cnt : 1);
    unsigned short lo = (unsigned short)f2bf(ax * inv);
    unsigned short hi = (unsigned short)f2bf(ay * inv);
    *(unsigned*)(agg + (size_t)n * 384 + r * 128 + lane * 2) = (unsigned)lo | ((unsigned)hi << 16);
}

// ---- classifier + masked CE loss (lm bf16, g bf16) + fused finalize ----
__global__ __launch_bounds__(256) void cls_loss_kernel(
    const short* __restrict__ lm, const short* __restrict__ g,
    const float* __restrict__ clsW, const float* __restrict__ clsb,
    const int* __restrict__ mask, const int* __restrict__ labels,
    float* __restrict__ logits, float* __restrict__ accb,
    unsigned* __restrict__ ticket, float* __restrict__ loss_out)
{
    __shared__ float W[2048];
    for (int i = threadIdx.x; i < 2048; i += 256) W[i] = clsW[i];
    __syncthreads();
    int n = blockIdx.x * 256 + threadIdx.x;
    float l[8];
    #pragma unroll
    for (int c = 0; c < 8; ++c) l[c] = clsb[c];
    const short* lmr = lm + (size_t)n * 128;
    const short* gr  = g  + (size_t)n * 128;
    #pragma unroll 2
    for (int h = 0; h < 128; h += 8) {
        uint4 raw = *(const uint4*)(lmr + h);
        float a[8];
        a[0] = bf2f((unsigned short)(raw.x & 0xffff)); a[1] = bf2f((unsigned short)(raw.x >> 16));
        a[2] = bf2f((unsigned short)(raw.y & 0xffff)); a[3] = bf2f((unsigned short)(raw.y >> 16));
        a[4] = bf2f((unsigned short)(raw.z & 0xffff)); a[5] = bf2f((unsigned short)(raw.z >> 16));
        a[6] = bf2f((unsigned short)(raw.w & 0xffff)); a[7] = bf2f((unsigned short)(raw.w >> 16));
        #pragma unroll
        for (int c = 0; c < 8; ++c) {
            const float* w = &W[c * 256 + h];
            #pragma unroll
            for (int j = 0; j < 8; ++j) l[c] = fmaf(a[j], w[j], l[c]);
        }
    }
    #pragma unroll 2
    for (int h = 0; h < 128; h += 8) {
        uint4 raw = *(const uint4*)(gr + h);
        float a[8];
        a[0] = bf2f((unsigned short)(raw.x & 0xffff)); a[1] = bf2f((unsigned short)(raw.x >> 16));
        a[2] = bf2f((unsigned short)(raw.y & 0xffff)); a[3] = bf2f((unsigned short)(raw.y >> 16));
        a[4] = bf2f((unsigned short)(raw.z & 0xffff)); a[5] = bf2f((unsigned short)(raw.z >> 16));
        a[6] = bf2f((unsigned short)(raw.w & 0xffff)); a[7] = bf2f((unsigned short)(raw.w >> 16));
        #pragma unroll
        for (int c = 0; c < 8; ++c) {
            const float* w = &W[c * 256 + 128 + h];
            #pragma unroll
            for (int j = 0; j < 8; ++j) l[c] = fmaf(a[j], w[j], l[c]);
        }
    }
    #pragma unroll
    for (int c = 0; c < 8; ++c) logits[(size_t)n * 8 + c] = l[c];

    float m = l[0];
    #pragma unroll
    for (int c = 1; c < 8; ++c) m = fmaxf(m, l[c]);
    float ss = 0.f;
    #pragma unroll
    for (int c = 0; c < 8; ++c) ss += expf(l[c] - m);
    float lse = m + logf(ss);
    int y = labels[n];
    float ly = l[0];
    #pragma unroll
    for (int c = 1; c < 8; ++c) ly = (y == c) ? l[c] : ly;
    float nll = lse - ly;
    bool valid = (mask[n] == 1);
    float lv = valid ? nll : 0.f;
    float cv = valid ? 1.f : 0.f;
    #pragma unroll
    for (int off = 32; off > 0; off >>= 1) {
        lv += __shfl_down(lv, off, 64);
        cv += __shfl_down(cv, off, 64);
    }
    if ((threadIdx.x & 63) == 0) { atomicAdd(&accb[0], lv); atomicAdd(&accb[1], cv); }

    // last-block finalize (device-scope atomics; accb adds precede ticket in
    // program order, fence makes them visible before ticket increments)
    __threadfence();
    if (threadIdx.x == 0) {
        unsigned t = atomicAdd(ticket, 1u);
        if (t == gridDim.x - 1) {
            float lsum = atomicAdd(&accb[0], 0.f);   // coherent read
            float csum = atomicAdd(&accb[1], 0.f);
            loss_out[0] = lsum / fmaxf(csum, 1.f);
        }
    }
}

// ---- launcher ----
extern "C" void kernel_launch(void* const* d_in, const int* in_sizes, int n_in,
                              void* d_out, int out_size, void* d_ws, size_t ws_size,
                              hipStream_t stream)
{
    const float* output = (const float*)d_in[0];
    const int* edge_index = (const int*)d_in[1];
    const int* edge_type  = (const int*)d_in[2];
    const int* attn       = (const int*)d_in[3];
    const int* labels     = (const int*)d_in[4];
    const float* lmW   = (const float*)d_in[5];
    const float* lmb   = (const float*)d_in[6];
    const float* lng   = (const float*)d_in[7];
    const float* lnb   = (const float*)d_in[8];
    const float* Wrel  = (const float*)d_in[9];
    const float* Wroot = (const float*)d_in[10];
    const float* convb = (const float*)d_in[11];
    const float* clsW  = (const float*)d_in[12];
    const float* clsb  = (const float*)d_in[13];

    char* ws = (char*)d_ws;
    short* lm_bf  = (short*)ws;                          ws += (size_t)Nn * Dd * 2;
    short* x1_bf  = (short*)ws;                          ws += (size_t)Nn * Dd * 2;
    short* x2_bf  = (short*)ws;                          ws += (size_t)Nn * Dd * 2;
    short* agg_bf = (short*)ws;                          ws += (size_t)Nn * 384 * 2;
    short* Wp_all = (short*)ws;                          ws += (size_t)262144 * 2;
    // zeroed region: [accb+ticket pad | counts | fill] contiguous
    float* accb   = (float*)ws;                          ws += 64;
    int* counts   = (int*)ws;                            ws += (size_t)NSEG * 4;
    int* fill     = (int*)ws;                            ws += (size_t)NSEG * 4;
    int* row_ptr  = (int*)ws;                            ws += (size_t)(NSEG + 4) * 4;
    int* excl     = (int*)ws;                            ws += (size_t)NSEG * 4;
    int* blksum   = (int*)ws;                            ws += 512 * 4;
    int* edge_src = (int*)ws;

    unsigned* ticket = (unsigned*)(accb + 2);            // inside zeroed pad

    short* Wp_lm = Wp_all;
    short* Wp_c0 = Wp_all + 131072;
    short* Wp_c1 = Wp_all + 131072 + 65536;

    const int* e_src = edge_index;
    const int* e_dst = edge_index + Ee;

    hipMemsetAsync(accb, 0, 64 + 2 * (size_t)NSEG * 4, stream);

    // pack weights + edge histogram (fused, independent halves)
    prep_kernel<<<dim3(1024 + Ee / 256), dim3(256), 0, stream>>>(
        lmW, Wrel, Wroot, Wp_all, e_dst, edge_type, counts);

    // LM head + ReLU + fused LN (bf16 out only)
    lm_gemm_ln_kernel<<<dim3(Nn / 64), dim3(256), 0, stream>>>(
        output, Wp_lm, lmb, lng, lnb, lm_bf);

    // CSR over (dst, relation)
    scan_blk_kernel<<<dim3(NSEG / 256), dim3(256), 0, stream>>>(counts, excl, blksum);
    scan_add_kernel<<<dim3(NSEG / 256), dim3(256), 0, stream>>>(excl, blksum, row_ptr);
    scatter_kernel<<<dim3(Ee / 256), dim3(256), 0, stream>>>(
        e_src, e_dst, edge_type, row_ptr, fill, edge_src);

    // RGCN layers
    aggregate_kernel<<<dim3(NSEG / 4), dim3(256), 0, stream>>>(lm_bf, row_ptr, edge_src, agg_bf);
    conv_gemm_kernel<<<dim3(Nn / 64), dim3(256), 0, stream>>>(
        agg_bf, lm_bf, Wp_c0, convb, x1_bf);
    aggregate_kernel<<<dim3(NSEG / 4), dim3(256), 0, stream>>>(x1_bf, row_ptr, edge_src, agg_bf);
    conv_gemm_kernel<<<dim3(Nn / 64), dim3(256), 0, stream>>>(
        agg_bf, x1_bf, Wp_c1, convb + Dd, x2_bf);

    // classifier + loss + fused finalize
    float* logits = (float*)d_out + 1;
    cls_loss_kernel<<<dim3(Nn / 256), dim3(256), 0, stream>>>(
        lm_bf, x2_bf, clsW, clsb, attn, labels, logits, accb, ticket, (float*)d_out);
}